// Round 12
// baseline (132.578 us; speedup 1.0000x reference)
//
#include <hip/hip_runtime.h>
#include <hip/hip_bf16.h>

#define NROW 8192   // B*A = 64*128
#define INC  128
#define OUTC 64

typedef __bf16 bf16x8 __attribute__((ext_vector_type(8)));
typedef __bf16 bf16x4 __attribute__((ext_vector_type(4)));
typedef short  s16x4  __attribute__((ext_vector_type(4)));
typedef float  f32x4  __attribute__((ext_vector_type(4)));

static __device__ __forceinline__ f32x4 mfma16(bf16x8 a, bf16x8 b, f32x4 c) {
    return __builtin_amdgcn_mfma_f32_16x16x32_bf16(a, b, c, 0, 0, 0);
}
// 16x16x16 bf16 (K=16). C/D of S^T in this shape IS the A-operand layout of P
// for the PV mfma -> no transpose needed between QK^T and PV.
static __device__ __forceinline__ f32x4 mfma1k(s16x4 a, s16x4 b, f32x4 c) {
    return __builtin_amdgcn_mfma_f32_16x16x16bf16_1k(a, b, c, 0, 0, 0);
}

static __device__ __forceinline__ bf16x8 cvt8(float4 lo, float4 hi) {
    bf16x8 r;
    r[0] = (__bf16)lo.x; r[1] = (__bf16)lo.y; r[2] = (__bf16)lo.z; r[3] = (__bf16)lo.w;
    r[4] = (__bf16)hi.x; r[5] = (__bf16)hi.y; r[6] = (__bf16)hi.z; r[7] = (__bf16)hi.w;
    return r;
}

// ---------------------------------------------------------------------------
// Kernel 1: projection via MFMA. grid = 768 = mat(3) x b(64) x aq(4).
// Q/K/V written in FRAGMENT-TILED layout for attn (512-B tiles, see r10),
// plus row-l2-normalized vnb (row-major) for the sim GEMM.
__global__ __launch_bounds__(256) void proj_kernel(
    const float* __restrict__ feat,
    const float* __restrict__ Wq, const float* __restrict__ bq,
    const float* __restrict__ Wk, const float* __restrict__ bk,
    const float* __restrict__ Wv, const float* __restrict__ bv,
    __hip_bfloat16* __restrict__ qbf, __hip_bfloat16* __restrict__ kbf,
    __hip_bfloat16* __restrict__ vbf, __hip_bfloat16* __restrict__ vnb)
{
    __shared__ float slab[32 * 132];
    __shared__ float vbuf[32 * 66];
    __shared__ float invb[32];

    const int blk = blockIdx.x;
    const int mat = blk >> 8;
    const int b   = (blk >> 2) & 63;
    const int a0  = (blk & 3) * 32;
    const int r0  = b * 128 + a0;
    const float* fb = feat + (size_t)b * INC * 128;

    for (int i = threadIdx.x; i < 32 * 128; i += 256) {
        int c = i >> 5, a = i & 31;
        slab[a * 132 + c] = fb[c * 128 + a0 + a];
    }
    __syncthreads();

    const int w    = threadIdx.x >> 6;
    const int lane = threadIdx.x & 63;
    const int l16  = lane & 15;
    const int quad = lane >> 4;
    const int n0   = w * 16;

    const float* W    = (mat == 0) ? Wq : (mat == 1) ? Wk : Wv;
    const float* bias = (mat == 0) ? bq : (mat == 1) ? bk : bv;

    f32x4 acc[2] = {{0.f,0.f,0.f,0.f},{0.f,0.f,0.f,0.f}};
    #pragma unroll
    for (int kc = 0; kc < 4; ++kc) {
        const int k0 = kc * 32 + quad * 8;
        const float* wr = W + (n0 + l16) * INC + k0;
        bf16x8 bfr = cvt8(*(const float4*)wr, *(const float4*)(wr + 4));
        #pragma unroll
        for (int u = 0; u < 2; ++u) {
            const float* ar = slab + (u * 16 + l16) * 132 + k0;
            bf16x8 afr = cvt8(*(const float4*)ar, *(const float4*)(ar + 4));
            acc[u] = mfma16(afr, bfr, acc[u]);
        }
    }
    const float bl = bias[n0 + l16];

    if (mat < 2) {
        __hip_bfloat16* dst = mat ? kbf : qbf;
        #pragma unroll
        for (int u = 0; u < 2; ++u) {
            const int base = ((((r0 >> 4) + u) * 4 + w) << 8) + l16;
            #pragma unroll
            for (int r = 0; r < 4; ++r)
                dst[base + (quad * 4 + r) * 16] = __float2bfloat16(acc[u][r] + bl);
        }
    } else {
        #pragma unroll
        for (int u = 0; u < 2; ++u)
            #pragma unroll
            for (int r = 0; r < 4; ++r)
                vbuf[(u * 16 + quad * 4 + r) * 66 + n0 + l16] = acc[u][r] + bl;
        __syncthreads();
        const int rl = threadIdx.x >> 3;
        const int jj = threadIdx.x & 7;
        float ss = 0.f;
        #pragma unroll
        for (int i = 0; i < 8; ++i) {
            float x = vbuf[rl * 66 + jj * 8 + i];
            ss += x * x;
        }
        ss += __shfl_xor(ss, 1, 64);
        ss += __shfl_xor(ss, 2, 64);
        ss += __shfl_xor(ss, 4, 64);
        if (jj == 0) invb[rl] = rsqrtf(fmaxf(ss, 1e-24f));
        __syncthreads();
        float inv = invb[rl];
        bf16x8 vp;
        #pragma unroll
        for (int i = 0; i < 8; ++i)
            vp[i] = (__bf16)(vbuf[rl * 66 + jj * 8 + i] * inv);
        *(bf16x8*)(vnb + (size_t)(r0 + rl) * 64 + jj * 8) = vp;
        const int tl = threadIdx.x & 15;
        const int n  = (threadIdx.x >> 4) & 3;
        const int s_ = threadIdx.x >> 6;
        bf16x8 pack;
        #pragma unroll
        for (int j = 0; j < 8; ++j) {
            int key = s_ * 8 + j;
            pack[j] = (__bf16)(vbuf[key * 66 + n * 16 + tl] * invb[key]);
        }
        const int base = ((((r0 >> 4) + (s_ >> 1)) * 4 + n) << 8) + tl * 16 + (s_ & 1) * 8;
        *(bf16x8*)(vbf + base) = pack;
    }
}

// ---------------------------------------------------------------------------
// Kernel 2: attention — K=16 no-transpose register pipeline.
// grid = 2048 = qtile(256) x bg(8); 4 waves/block, wave w owns keys
// [bg*1024 + w*256, +256) = 8 iters of 32 keys. Epilogue: 2-slab LDS tree
// reduction (17 KB -> ~7 blocks/CU co-resident; r11's 33-KB 4-slab version
// plus G=2 grid left only 2 waves/SIMD -> latency-starved at 49 us).
__global__ __launch_bounds__(256) void attn_kernel(
    const __hip_bfloat16* __restrict__ qbf,
    const __hip_bfloat16* __restrict__ kbf,
    const __hip_bfloat16* __restrict__ vbf,
    float* __restrict__ Opart, float* __restrict__ lpart)
{
    __shared__ float ored[2][32][65];   // [slab][row][col], pad-65
    __shared__ float lred[2][32];

    const int qtile = blockIdx.x >> 3;
    const int bg    = blockIdx.x & 7;
    const int w     = threadIdx.x >> 6;
    const int lane  = threadIdx.x & 63;
    const int l16   = lane & 15;
    const int quad  = lane >> 4;
    const int r0    = qtile * 32;
    const int fo    = l16 * 16 + quad * 4;   // elem offset inside a 256-elem tile

    s16x4 qf[2][4];
    #pragma unroll
    for (int u = 0; u < 2; ++u)
        #pragma unroll
        for (int kc = 0; kc < 4; ++kc)
            qf[u][kc] = *(const s16x4*)(qbf + ((((r0 >> 4) + u) * 4 + kc) << 8) + fo);

    f32x4 of[2][4];
    float lp[2] = {0.f, 0.f};
    #pragma unroll
    for (int u = 0; u < 2; ++u)
        #pragma unroll
        for (int n = 0; n < 4; ++n)
            of[u][n] = (f32x4){0.f, 0.f, 0.f, 0.f};

    const float coef = 0.18033688011112042f;   // log2(e) / sqrt(64)

    int ck = bg * 64 + w * 16;                 // key 16-chunk index
    s16x4 kf[2][4];
    #pragma unroll
    for (int h = 0; h < 2; ++h)
        #pragma unroll
        for (int kc = 0; kc < 4; ++kc)
            kf[h][kc] = *(const s16x4*)(kbf + (((ck + h) * 4 + kc) << 8) + fo);

    #pragma unroll 1
    for (int it = 0; it < 8; ++it) {
        s16x4 vf[4][2];
        #pragma unroll
        for (int n = 0; n < 4; ++n)
            #pragma unroll
            for (int h = 0; h < 2; ++h)
                vf[n][h] = *(const s16x4*)(vbf + (((ck + h) * 4 + n) << 8) + fo);
        const int cn = (it < 7) ? ck + 2 : ck;
        s16x4 kn[2][4];
        #pragma unroll
        for (int h = 0; h < 2; ++h)
            #pragma unroll
            for (int kc = 0; kc < 4; ++kc)
                kn[h][kc] = *(const s16x4*)(kbf + (((cn + h) * 4 + kc) << 8) + fo);

        const f32x4 zero = (f32x4){0.f, 0.f, 0.f, 0.f};
        #pragma unroll
        for (int u = 0; u < 2; ++u) {
            f32x4 s0 = zero, s1 = zero;
            #pragma unroll
            for (int kc = 0; kc < 4; ++kc) {
                s0 = mfma1k(kf[0][kc], qf[u][kc], s0);
                s1 = mfma1k(kf[1][kc], qf[u][kc], s1);
            }
            union { bf16x4 v; s16x4 s; } pf0, pf1;
            #pragma unroll
            for (int r = 0; r < 4; ++r) {
                float p0 = exp2f(s0[r] * coef);
                float p1 = exp2f(s1[r] * coef);
                lp[u] += p0 + p1;
                pf0.v[r] = (__bf16)p0;
                pf1.v[r] = (__bf16)p1;
            }
            #pragma unroll
            for (int n = 0; n < 4; ++n) {
                of[u][n] = mfma1k(pf0.s, vf[n][0], of[u][n]);
                of[u][n] = mfma1k(pf1.s, vf[n][1], of[u][n]);
            }
        }
        #pragma unroll
        for (int h = 0; h < 2; ++h)
            #pragma unroll
            for (int kc = 0; kc < 4; ++kc)
                kf[h][kc] = kn[h][kc];
        ck += 2;
    }

    // per-wave l reduction across quads (uniform across lanes afterwards)
    #pragma unroll
    for (int u = 0; u < 2; ++u) {
        float v = lp[u];
        v += __shfl_xor(v, 16, 64);
        v += __shfl_xor(v, 32, 64);
        lp[u] = v;
    }

    // 2-slab tree reduction: waves 2,3 -> LDS
    if (w >= 2) {
        #pragma unroll
        for (int u = 0; u < 2; ++u)
            #pragma unroll
            for (int n = 0; n < 4; ++n)
                #pragma unroll
                for (int r = 0; r < 4; ++r)
                    ored[w - 2][u * 16 + quad * 4 + r][n * 16 + l16] = of[u][n][r];
        if (quad == 0) {
            lred[w - 2][l16]      = lp[0];
            lred[w - 2][16 + l16] = lp[1];
        }
    }
    __syncthreads();
    // waves 0,1 add partner slab in-register, write back
    if (w < 2) {
        #pragma unroll
        for (int u = 0; u < 2; ++u)
            #pragma unroll
            for (int n = 0; n < 4; ++n)
                #pragma unroll
                for (int r = 0; r < 4; ++r) {
                    float v = of[u][n][r] + ored[w][u * 16 + quad * 4 + r][n * 16 + l16];
                    ored[w][u * 16 + quad * 4 + r][n * 16 + l16] = v;
                }
        if (quad == 0) {
            lred[w][l16]      += lp[0];
            lred[w][16 + l16] += lp[1];
        }
    }
    __syncthreads();
    // final merge, one 32x64 fp32 partial per block
    const int task = blockIdx.x;
    float* Ob = Opart + (size_t)task * 2048;
    for (int e = threadIdx.x; e < 2048; e += 256) {
        const int row = e >> 6, col = e & 63;
        Ob[e] = ored[0][row][col] + ored[1][row][col];
    }
    if (threadIdx.x < 32)
        lpart[task * 32 + threadIdx.x] = lred[0][threadIdx.x] + lred[1][threadIdx.x];
}

// ---------------------------------------------------------------------------
// Kernel 3: combine 8 partials/tile, divide by l, l2-normalize -> qnb (bf16).
__global__ __launch_bounds__(256) void combine_kernel(
    const float* __restrict__ Opart, const float* __restrict__ lpart,
    __hip_bfloat16* __restrict__ qnb)
{
    const int r    = blockIdx.x * 4 + (threadIdx.x >> 6);
    const int c    = threadIdx.x & 63;
    const int tile = r >> 5, row = r & 31;
    float acc = 0.f, lsum = 0.f;
    #pragma unroll
    for (int g = 0; g < 8; ++g) {
        int task = tile * 8 + g;
        acc  += Opart[(size_t)task * 2048 + row * 64 + c];
        lsum += lpart[task * 32 + row];
    }
    float q = acc / lsum;
    float ss = q * q;
    ss += __shfl_xor(ss, 1, 64);
    ss += __shfl_xor(ss, 2, 64);
    ss += __shfl_xor(ss, 4, 64);
    ss += __shfl_xor(ss, 8, 64);
    ss += __shfl_xor(ss, 16, 64);
    ss += __shfl_xor(ss, 32, 64);
    qnb[(size_t)r * 64 + c] = __float2bfloat16(q * rsqrtf(fmaxf(ss, 1e-24f)));
}

// ---------------------------------------------------------------------------
// Kernel 4: sim = (1/128) * Vn(64x8192) @ Qn(64x8192)^T, split-K MFMA GEMM.
__global__ __launch_bounds__(64) void sim_kernel(
    const __hip_bfloat16* __restrict__ vnb,
    const __hip_bfloat16* __restrict__ qnb,
    float* __restrict__ out)
{
    const int lane = threadIdx.x;
    const int l16  = lane & 15;
    const int quad = lane >> 4;
    const int kblk = blockIdx.x * 256;

    f32x4 acc[4][4];
    #pragma unroll
    for (int mi = 0; mi < 4; ++mi)
        #pragma unroll
        for (int ni = 0; ni < 4; ++ni)
            acc[mi][ni] = (f32x4){0.f, 0.f, 0.f, 0.f};

    #pragma unroll
    for (int ks = 0; ks < 8; ++ks) {
        const int k0 = kblk + ks * 32 + quad * 8;
        bf16x8 af[4], bfv[4];
        #pragma unroll
        for (int mi = 0; mi < 4; ++mi)
            af[mi] = *(const bf16x8*)(vnb + (size_t)(mi * 16 + l16) * 8192 + k0);
        #pragma unroll
        for (int ni = 0; ni < 4; ++ni)
            bfv[ni] = *(const bf16x8*)(qnb + (size_t)(ni * 16 + l16) * 8192 + k0);
        #pragma unroll
        for (int mi = 0; mi < 4; ++mi)
            #pragma unroll
            for (int ni = 0; ni < 4; ++ni)
                acc[mi][ni] = mfma16(af[mi], bfv[ni], acc[mi][ni]);
    }

    #pragma unroll
    for (int mi = 0; mi < 4; ++mi)
        #pragma unroll
        for (int ni = 0; ni < 4; ++ni)
            #pragma unroll
            for (int r = 0; r < 4; ++r)
                atomicAdd(&out[(mi * 16 + quad * 4 + r) * 64 + ni * 16 + l16],
                          acc[mi][ni][r] * (1.f / 128.f));
}

// ---------------------------------------------------------------------------
extern "C" void kernel_launch(void* const* d_in, const int* in_sizes, int n_in,
                              void* d_out, int out_size, void* d_ws, size_t ws_size,
                              hipStream_t stream)
{
    const float* feat = (const float*)d_in[0];
    const float* Wq   = (const float*)d_in[1];
    const float* bq   = (const float*)d_in[2];
    const float* Wk   = (const float*)d_in[3];
    const float* bk   = (const float*)d_in[4];
    const float* Wv   = (const float*)d_in[5];
    const float* bv   = (const float*)d_in[6];
    float* out = (float*)d_out;

    const size_t MB = 1u << 20;
    char* ws = (char*)d_ws;
    __hip_bfloat16* qbf = (__hip_bfloat16*)(ws);              // 1 MB (frag-tiled)
    __hip_bfloat16* kbf = (__hip_bfloat16*)(ws + 1 * MB);     // 1 MB (frag-tiled)
    __hip_bfloat16* vbf = (__hip_bfloat16*)(ws + 2 * MB);     // 1 MB (frag-tiled)
    __hip_bfloat16* vnb = (__hip_bfloat16*)(ws + 3 * MB);     // 1 MB (row-major)
    float* Opart = (float*)(ws + 4 * MB);                     // 16 MB (2048 x 8 KB)
    float* lpart = (float*)(ws + 20 * MB);                    // 256 KB
    __hip_bfloat16* qnb = (__hip_bfloat16*)(ws + 21 * MB);    // 1 MB

    (void)hipMemsetAsync(out, 0, 64 * 64 * sizeof(float), stream);
    proj_kernel<<<768, 256, 0, stream>>>(feat, Wq, bq, Wk, bk, Wv, bv, qbf, kbf, vbf, vnb);
    attn_kernel<<<2048, 256, 0, stream>>>(qbf, kbf, vbf, Opart, lpart);
    combine_kernel<<<2048, 256, 0, stream>>>(Opart, lpart, qnb);
    sim_kernel<<<32, 64, 0, stream>>>(vnb, qnb, out);
}

// Round 13
// 123.496 us; speedup vs baseline: 1.0735x; 1.0735x over previous
//
#include <hip/hip_runtime.h>
#include <hip/hip_bf16.h>

#define NROW 8192   // B*A = 64*128
#define INC  128
#define OUTC 64

// Q is pre-scaled by log2(e)/sqrt(64) at projection time, so attention
// computes p = exp2(q'.k) with a single v_exp_f32 per score.
#define QSCALE 0.18033688011112042f

typedef __bf16 bf16x8 __attribute__((ext_vector_type(8)));
typedef __bf16 bf16x4 __attribute__((ext_vector_type(4)));
typedef short  s16x4  __attribute__((ext_vector_type(4)));
typedef float  f32x4  __attribute__((ext_vector_type(4)));

static __device__ __forceinline__ f32x4 mfma16(bf16x8 a, bf16x8 b, f32x4 c) {
    return __builtin_amdgcn_mfma_f32_16x16x32_bf16(a, b, c, 0, 0, 0);
}
// 16x16x16 bf16 (K=16). C/D of S^T in this shape IS the A-operand layout of P
// for the PV mfma -> no transpose needed between QK^T and PV.
static __device__ __forceinline__ f32x4 mfma1k(s16x4 a, s16x4 b, f32x4 c) {
    return __builtin_amdgcn_mfma_f32_16x16x16bf16_1k(a, b, c, 0, 0, 0);
}

static __device__ __forceinline__ bf16x8 cvt8(float4 lo, float4 hi) {
    bf16x8 r;
    r[0] = (__bf16)lo.x; r[1] = (__bf16)lo.y; r[2] = (__bf16)lo.z; r[3] = (__bf16)lo.w;
    r[4] = (__bf16)hi.x; r[5] = (__bf16)hi.y; r[6] = (__bf16)hi.z; r[7] = (__bf16)hi.w;
    return r;
}

// ---------------------------------------------------------------------------
// Kernel 1: projection via MFMA. grid = 768 = mat(3) x b(64) x aq(4).
// Q/K/V written in FRAGMENT-TILED layout for attn (512-B tiles, see r10),
// Q pre-scaled by QSCALE (fp32, before bf16 rounding -> no precision loss).
__global__ __launch_bounds__(256) void proj_kernel(
    const float* __restrict__ feat,
    const float* __restrict__ Wq, const float* __restrict__ bq,
    const float* __restrict__ Wk, const float* __restrict__ bk,
    const float* __restrict__ Wv, const float* __restrict__ bv,
    __hip_bfloat16* __restrict__ qbf, __hip_bfloat16* __restrict__ kbf,
    __hip_bfloat16* __restrict__ vbf, __hip_bfloat16* __restrict__ vnb)
{
    __shared__ float slab[32 * 132];
    __shared__ float vbuf[32 * 66];
    __shared__ float invb[32];

    const int blk = blockIdx.x;
    const int mat = blk >> 8;
    const int b   = (blk >> 2) & 63;
    const int a0  = (blk & 3) * 32;
    const int r0  = b * 128 + a0;
    const float* fb = feat + (size_t)b * INC * 128;

    for (int i = threadIdx.x; i < 32 * 128; i += 256) {
        int c = i >> 5, a = i & 31;
        slab[a * 132 + c] = fb[c * 128 + a0 + a];
    }
    __syncthreads();

    const int w    = threadIdx.x >> 6;
    const int lane = threadIdx.x & 63;
    const int l16  = lane & 15;
    const int quad = lane >> 4;
    const int n0   = w * 16;

    const float* W    = (mat == 0) ? Wq : (mat == 1) ? Wk : Wv;
    const float* bias = (mat == 0) ? bq : (mat == 1) ? bk : bv;

    f32x4 acc[2] = {{0.f,0.f,0.f,0.f},{0.f,0.f,0.f,0.f}};
    #pragma unroll
    for (int kc = 0; kc < 4; ++kc) {
        const int k0 = kc * 32 + quad * 8;
        const float* wr = W + (n0 + l16) * INC + k0;
        bf16x8 bfr = cvt8(*(const float4*)wr, *(const float4*)(wr + 4));
        #pragma unroll
        for (int u = 0; u < 2; ++u) {
            const float* ar = slab + (u * 16 + l16) * 132 + k0;
            bf16x8 afr = cvt8(*(const float4*)ar, *(const float4*)(ar + 4));
            acc[u] = mfma16(afr, bfr, acc[u]);
        }
    }
    const float bl = bias[n0 + l16];
    const float sc = (mat == 0) ? QSCALE : 1.0f;

    if (mat < 2) {
        __hip_bfloat16* dst = mat ? kbf : qbf;
        #pragma unroll
        for (int u = 0; u < 2; ++u) {
            const int base = ((((r0 >> 4) + u) * 4 + w) << 8) + l16;
            #pragma unroll
            for (int r = 0; r < 4; ++r)
                dst[base + (quad * 4 + r) * 16] = __float2bfloat16((acc[u][r] + bl) * sc);
        }
    } else {
        #pragma unroll
        for (int u = 0; u < 2; ++u)
            #pragma unroll
            for (int r = 0; r < 4; ++r)
                vbuf[(u * 16 + quad * 4 + r) * 66 + n0 + l16] = acc[u][r] + bl;
        __syncthreads();
        const int rl = threadIdx.x >> 3;
        const int jj = threadIdx.x & 7;
        float ss = 0.f;
        #pragma unroll
        for (int i = 0; i < 8; ++i) {
            float x = vbuf[rl * 66 + jj * 8 + i];
            ss += x * x;
        }
        ss += __shfl_xor(ss, 1, 64);
        ss += __shfl_xor(ss, 2, 64);
        ss += __shfl_xor(ss, 4, 64);
        if (jj == 0) invb[rl] = rsqrtf(fmaxf(ss, 1e-24f));
        __syncthreads();
        float inv = invb[rl];
        bf16x8 vp;
        #pragma unroll
        for (int i = 0; i < 8; ++i)
            vp[i] = (__bf16)(vbuf[rl * 66 + jj * 8 + i] * inv);
        *(bf16x8*)(vnb + (size_t)(r0 + rl) * 64 + jj * 8) = vp;
        const int tl = threadIdx.x & 15;
        const int n  = (threadIdx.x >> 4) & 3;
        const int s_ = threadIdx.x >> 6;
        bf16x8 pack;
        #pragma unroll
        for (int j = 0; j < 8; ++j) {
            int key = s_ * 8 + j;
            pack[j] = (__bf16)(vbuf[key * 66 + n * 16 + tl] * invb[key]);
        }
        const int base = ((((r0 >> 4) + (s_ >> 1)) * 4 + n) << 8) + tl * 16 + (s_ & 1) * 8;
        *(bf16x8*)(vbf + base) = pack;
    }
}

// ---------------------------------------------------------------------------
// Kernel 2: attention — K=16 no-transpose register pipeline, VALU-trimmed:
// raw v_exp_f32 (args bounded, no libm fixups) and no per-score coef mul
// (Q pre-scaled in proj). grid = 1024 = qtile(256) x bg(4); 4 waves/block,
// wave w owns keys [bg*2048 + w*512, +512) = 16 iters of 32 keys.
// Epilogue: 2-slab LDS tree reduction, one 32x64 fp32 partial per block.
__global__ __launch_bounds__(256) void attn_kernel(
    const __hip_bfloat16* __restrict__ qbf,
    const __hip_bfloat16* __restrict__ kbf,
    const __hip_bfloat16* __restrict__ vbf,
    float* __restrict__ Opart, float* __restrict__ lpart)
{
    __shared__ float ored[2][32][65];   // [slab][row][col], pad-65
    __shared__ float lred[2][32];

    const int qtile = blockIdx.x >> 2;
    const int bg    = blockIdx.x & 3;
    const int w     = threadIdx.x >> 6;
    const int lane  = threadIdx.x & 63;
    const int l16   = lane & 15;
    const int quad  = lane >> 4;
    const int r0    = qtile * 32;
    const int fo    = l16 * 16 + quad * 4;   // elem offset inside a 256-elem tile

    s16x4 qf[2][4];
    #pragma unroll
    for (int u = 0; u < 2; ++u)
        #pragma unroll
        for (int kc = 0; kc < 4; ++kc)
            qf[u][kc] = *(const s16x4*)(qbf + ((((r0 >> 4) + u) * 4 + kc) << 8) + fo);

    f32x4 of[2][4];
    float lp[2] = {0.f, 0.f};
    #pragma unroll
    for (int u = 0; u < 2; ++u)
        #pragma unroll
        for (int n = 0; n < 4; ++n)
            of[u][n] = (f32x4){0.f, 0.f, 0.f, 0.f};

    int ck = bg * 128 + w * 32;                // key 16-chunk index
    s16x4 kf[2][4];
    #pragma unroll
    for (int h = 0; h < 2; ++h)
        #pragma unroll
        for (int kc = 0; kc < 4; ++kc)
            kf[h][kc] = *(const s16x4*)(kbf + (((ck + h) * 4 + kc) << 8) + fo);

    #pragma unroll 1
    for (int it = 0; it < 16; ++it) {
        s16x4 vf[4][2];
        #pragma unroll
        for (int n = 0; n < 4; ++n)
            #pragma unroll
            for (int h = 0; h < 2; ++h)
                vf[n][h] = *(const s16x4*)(vbf + (((ck + h) * 4 + n) << 8) + fo);
        const int cn = (it < 15) ? ck + 2 : ck;
        s16x4 kn[2][4];
        #pragma unroll
        for (int h = 0; h < 2; ++h)
            #pragma unroll
            for (int kc = 0; kc < 4; ++kc)
                kn[h][kc] = *(const s16x4*)(kbf + (((cn + h) * 4 + kc) << 8) + fo);

        const f32x4 zero = (f32x4){0.f, 0.f, 0.f, 0.f};
        #pragma unroll
        for (int u = 0; u < 2; ++u) {
            f32x4 s0 = zero, s1 = zero;
            #pragma unroll
            for (int kc = 0; kc < 4; ++kc) {
                s0 = mfma1k(kf[0][kc], qf[u][kc], s0);
                s1 = mfma1k(kf[1][kc], qf[u][kc], s1);
            }
            union { bf16x4 v; s16x4 s; } pf0, pf1;
            #pragma unroll
            for (int r = 0; r < 4; ++r) {
                float p0 = __builtin_amdgcn_exp2f(s0[r]);   // raw v_exp_f32
                float p1 = __builtin_amdgcn_exp2f(s1[r]);
                lp[u] += p0 + p1;
                pf0.v[r] = (__bf16)p0;
                pf1.v[r] = (__bf16)p1;
            }
            #pragma unroll
            for (int n = 0; n < 4; ++n) {
                of[u][n] = mfma1k(pf0.s, vf[n][0], of[u][n]);
                of[u][n] = mfma1k(pf1.s, vf[n][1], of[u][n]);
            }
        }
        #pragma unroll
        for (int h = 0; h < 2; ++h)
            #pragma unroll
            for (int kc = 0; kc < 4; ++kc)
                kf[h][kc] = kn[h][kc];
        ck += 2;
    }

    // per-wave l reduction across quads
    #pragma unroll
    for (int u = 0; u < 2; ++u) {
        float v = lp[u];
        v += __shfl_xor(v, 16, 64);
        v += __shfl_xor(v, 32, 64);
        lp[u] = v;
    }

    // 2-slab tree reduction: waves 2,3 -> LDS
    if (w >= 2) {
        #pragma unroll
        for (int u = 0; u < 2; ++u)
            #pragma unroll
            for (int n = 0; n < 4; ++n)
                #pragma unroll
                for (int r = 0; r < 4; ++r)
                    ored[w - 2][u * 16 + quad * 4 + r][n * 16 + l16] = of[u][n][r];
        if (quad == 0) {
            lred[w - 2][l16]      = lp[0];
            lred[w - 2][16 + l16] = lp[1];
        }
    }
    __syncthreads();
    if (w < 2) {
        #pragma unroll
        for (int u = 0; u < 2; ++u)
            #pragma unroll
            for (int n = 0; n < 4; ++n)
                #pragma unroll
                for (int r = 0; r < 4; ++r) {
                    float v = of[u][n][r] + ored[w][u * 16 + quad * 4 + r][n * 16 + l16];
                    ored[w][u * 16 + quad * 4 + r][n * 16 + l16] = v;
                }
        if (quad == 0) {
            lred[w][l16]      += lp[0];
            lred[w][16 + l16] += lp[1];
        }
    }
    __syncthreads();
    const int task = blockIdx.x;
    float* Ob = Opart + (size_t)task * 2048;
    for (int e = threadIdx.x; e < 2048; e += 256) {
        const int row = e >> 6, col = e & 63;
        Ob[e] = ored[0][row][col] + ored[1][row][col];
    }
    if (threadIdx.x < 32)
        lpart[task * 32 + threadIdx.x] = lred[0][threadIdx.x] + lred[1][threadIdx.x];
}

// ---------------------------------------------------------------------------
// Kernel 3: combine 4 partials/tile, divide by l, l2-normalize -> qnb (bf16).
__global__ __launch_bounds__(256) void combine_kernel(
    const float* __restrict__ Opart, const float* __restrict__ lpart,
    __hip_bfloat16* __restrict__ qnb)
{
    const int r    = blockIdx.x * 4 + (threadIdx.x >> 6);
    const int c    = threadIdx.x & 63;
    const int tile = r >> 5, row = r & 31;
    float acc = 0.f, lsum = 0.f;
    #pragma unroll
    for (int g = 0; g < 4; ++g) {
        int task = tile * 4 + g;
        acc  += Opart[(size_t)task * 2048 + row * 64 + c];
        lsum += lpart[task * 32 + row];
    }
    float q = acc / lsum;
    float ss = q * q;
    ss += __shfl_xor(ss, 1, 64);
    ss += __shfl_xor(ss, 2, 64);
    ss += __shfl_xor(ss, 4, 64);
    ss += __shfl_xor(ss, 8, 64);
    ss += __shfl_xor(ss, 16, 64);
    ss += __shfl_xor(ss, 32, 64);
    qnb[(size_t)r * 64 + c] = __float2bfloat16(q * rsqrtf(fmaxf(ss, 1e-24f)));
}

// ---------------------------------------------------------------------------
// Kernel 4: sim = (1/128) * Vn(64x8192) @ Qn(64x8192)^T, split-K MFMA GEMM.
__global__ __launch_bounds__(64) void sim_kernel(
    const __hip_bfloat16* __restrict__ vnb,
    const __hip_bfloat16* __restrict__ qnb,
    float* __restrict__ out)
{
    const int lane = threadIdx.x;
    const int l16  = lane & 15;
    const int quad = lane >> 4;
    const int kblk = blockIdx.x * 256;

    f32x4 acc[4][4];
    #pragma unroll
    for (int mi = 0; mi < 4; ++mi)
        #pragma unroll
        for (int ni = 0; ni < 4; ++ni)
            acc[mi][ni] = (f32x4){0.f, 0.f, 0.f, 0.f};

    #pragma unroll
    for (int ks = 0; ks < 8; ++ks) {
        const int k0 = kblk + ks * 32 + quad * 8;
        bf16x8 af[4], bfv[4];
        #pragma unroll
        for (int mi = 0; mi < 4; ++mi)
            af[mi] = *(const bf16x8*)(vnb + (size_t)(mi * 16 + l16) * 8192 + k0);
        #pragma unroll
        for (int ni = 0; ni < 4; ++ni)
            bfv[ni] = *(const bf16x8*)(qnb + (size_t)(ni * 16 + l16) * 8192 + k0);
        #pragma unroll
        for (int mi = 0; mi < 4; ++mi)
            #pragma unroll
            for (int ni = 0; ni < 4; ++ni)
                acc[mi][ni] = mfma16(af[mi], bfv[ni], acc[mi][ni]);
    }

    #pragma unroll
    for (int mi = 0; mi < 4; ++mi)
        #pragma unroll
        for (int ni = 0; ni < 4; ++ni)
            #pragma unroll
            for (int r = 0; r < 4; ++r)
                atomicAdd(&out[(mi * 16 + quad * 4 + r) * 64 + ni * 16 + l16],
                          acc[mi][ni][r] * (1.f / 128.f));
}

// ---------------------------------------------------------------------------
extern "C" void kernel_launch(void* const* d_in, const int* in_sizes, int n_in,
                              void* d_out, int out_size, void* d_ws, size_t ws_size,
                              hipStream_t stream)
{
    const float* feat = (const float*)d_in[0];
    const float* Wq   = (const float*)d_in[1];
    const float* bq   = (const float*)d_in[2];
    const float* Wk   = (const float*)d_in[3];
    const float* bk   = (const float*)d_in[4];
    const float* Wv   = (const float*)d_in[5];
    const float* bv   = (const float*)d_in[6];
    float* out = (float*)d_out;

    const size_t MB = 1u << 20;
    char* ws = (char*)d_ws;
    __hip_bfloat16* qbf = (__hip_bfloat16*)(ws);              // 1 MB (frag-tiled, pre-scaled)
    __hip_bfloat16* kbf = (__hip_bfloat16*)(ws + 1 * MB);     // 1 MB (frag-tiled)
    __hip_bfloat16* vbf = (__hip_bfloat16*)(ws + 2 * MB);     // 1 MB (frag-tiled)
    __hip_bfloat16* vnb = (__hip_bfloat16*)(ws + 3 * MB);     // 1 MB (row-major)
    float* Opart = (float*)(ws + 4 * MB);                     // 8 MB (1024 x 8 KB)
    float* lpart = (float*)(ws + 12 * MB);                    // 128 KB
    __hip_bfloat16* qnb = (__hip_bfloat16*)(ws + 13 * MB);    // 1 MB

    (void)hipMemsetAsync(out, 0, 64 * 64 * sizeof(float), stream);
    proj_kernel<<<768, 256, 0, stream>>>(feat, Wq, bq, Wk, bk, Wv, bv, qbf, kbf, vbf, vnb);
    attn_kernel<<<1024, 256, 0, stream>>>(qbf, kbf, vbf, Opart, lpart);
    combine_kernel<<<2048, 256, 0, stream>>>(Opart, lpart, qnb);
    sim_kernel<<<32, 64, 0, stream>>>(vnb, qnb, out);
}

// Round 14
// 122.543 us; speedup vs baseline: 1.0819x; 1.0078x over previous
//
#include <hip/hip_runtime.h>
#include <hip/hip_bf16.h>

#define NROW 8192   // B*A = 64*128
#define INC  128
#define OUTC 64

// Q is pre-scaled by log2(e)/sqrt(64) at projection time, so attention
// computes p = exp2(q'.k) with a single v_exp_f32 per score.
#define QSCALE 0.18033688011112042f

typedef __bf16 bf16x8 __attribute__((ext_vector_type(8)));
typedef __bf16 bf16x4 __attribute__((ext_vector_type(4)));
typedef short  s16x4  __attribute__((ext_vector_type(4)));
typedef float  f32x4  __attribute__((ext_vector_type(4)));

static __device__ __forceinline__ f32x4 mfma16(bf16x8 a, bf16x8 b, f32x4 c) {
    return __builtin_amdgcn_mfma_f32_16x16x32_bf16(a, b, c, 0, 0, 0);
}
// 16x16x16 bf16 (K=16). C/D of S^T IS the A-operand layout of P for PV.
static __device__ __forceinline__ f32x4 mfma1k(s16x4 a, s16x4 b, f32x4 c) {
    return __builtin_amdgcn_mfma_f32_16x16x16bf16_1k(a, b, c, 0, 0, 0);
}

static __device__ __forceinline__ bf16x8 cvt8(float4 lo, float4 hi) {
    bf16x8 r;
    r[0] = (__bf16)lo.x; r[1] = (__bf16)lo.y; r[2] = (__bf16)lo.z; r[3] = (__bf16)lo.w;
    r[4] = (__bf16)hi.x; r[5] = (__bf16)hi.y; r[6] = (__bf16)hi.z; r[7] = (__bf16)hi.w;
    return r;
}

// ---------------------------------------------------------------------------
// Kernel 1: projection via MFMA. grid = 768 = mat(3) x b(64) x aq(4).
// Q/K/V written in FRAGMENT-TILED layout (512-B 16x16 tiles), Q pre-scaled.
__global__ __launch_bounds__(256) void proj_kernel(
    const float* __restrict__ feat,
    const float* __restrict__ Wq, const float* __restrict__ bq,
    const float* __restrict__ Wk, const float* __restrict__ bk,
    const float* __restrict__ Wv, const float* __restrict__ bv,
    __hip_bfloat16* __restrict__ qbf, __hip_bfloat16* __restrict__ kbf,
    __hip_bfloat16* __restrict__ vbf, __hip_bfloat16* __restrict__ vnb)
{
    __shared__ float slab[32 * 132];
    __shared__ float vbuf[32 * 66];
    __shared__ float invb[32];

    const int blk = blockIdx.x;
    const int mat = blk >> 8;
    const int b   = (blk >> 2) & 63;
    const int a0  = (blk & 3) * 32;
    const int r0  = b * 128 + a0;
    const float* fb = feat + (size_t)b * INC * 128;

    for (int i = threadIdx.x; i < 32 * 128; i += 256) {
        int c = i >> 5, a = i & 31;
        slab[a * 132 + c] = fb[c * 128 + a0 + a];
    }
    __syncthreads();

    const int w    = threadIdx.x >> 6;
    const int lane = threadIdx.x & 63;
    const int l16  = lane & 15;
    const int quad = lane >> 4;
    const int n0   = w * 16;

    const float* W    = (mat == 0) ? Wq : (mat == 1) ? Wk : Wv;
    const float* bias = (mat == 0) ? bq : (mat == 1) ? bk : bv;

    f32x4 acc[2] = {{0.f,0.f,0.f,0.f},{0.f,0.f,0.f,0.f}};
    #pragma unroll
    for (int kc = 0; kc < 4; ++kc) {
        const int k0 = kc * 32 + quad * 8;
        const float* wr = W + (n0 + l16) * INC + k0;
        bf16x8 bfr = cvt8(*(const float4*)wr, *(const float4*)(wr + 4));
        #pragma unroll
        for (int u = 0; u < 2; ++u) {
            const float* ar = slab + (u * 16 + l16) * 132 + k0;
            bf16x8 afr = cvt8(*(const float4*)ar, *(const float4*)(ar + 4));
            acc[u] = mfma16(afr, bfr, acc[u]);
        }
    }
    const float bl = bias[n0 + l16];
    const float sc = (mat == 0) ? QSCALE : 1.0f;

    if (mat < 2) {
        __hip_bfloat16* dst = mat ? kbf : qbf;
        #pragma unroll
        for (int u = 0; u < 2; ++u) {
            const int base = ((((r0 >> 4) + u) * 4 + w) << 8) + l16;
            #pragma unroll
            for (int r = 0; r < 4; ++r)
                dst[base + (quad * 4 + r) * 16] = __float2bfloat16((acc[u][r] + bl) * sc);
        }
    } else {
        #pragma unroll
        for (int u = 0; u < 2; ++u)
            #pragma unroll
            for (int r = 0; r < 4; ++r)
                vbuf[(u * 16 + quad * 4 + r) * 66 + n0 + l16] = acc[u][r] + bl;
        __syncthreads();
        const int rl = threadIdx.x >> 3;
        const int jj = threadIdx.x & 7;
        float ss = 0.f;
        #pragma unroll
        for (int i = 0; i < 8; ++i) {
            float x = vbuf[rl * 66 + jj * 8 + i];
            ss += x * x;
        }
        ss += __shfl_xor(ss, 1, 64);
        ss += __shfl_xor(ss, 2, 64);
        ss += __shfl_xor(ss, 4, 64);
        if (jj == 0) invb[rl] = rsqrtf(fmaxf(ss, 1e-24f));
        __syncthreads();
        float inv = invb[rl];
        bf16x8 vp;
        #pragma unroll
        for (int i = 0; i < 8; ++i)
            vp[i] = (__bf16)(vbuf[rl * 66 + jj * 8 + i] * inv);
        *(bf16x8*)(vnb + (size_t)(r0 + rl) * 64 + jj * 8) = vp;
        const int tl = threadIdx.x & 15;
        const int n  = (threadIdx.x >> 4) & 3;
        const int s_ = threadIdx.x >> 6;
        bf16x8 pack;
        #pragma unroll
        for (int j = 0; j < 8; ++j) {
            int key = s_ * 8 + j;
            pack[j] = (__bf16)(vbuf[key * 66 + n * 16 + tl] * invb[key]);
        }
        const int base = ((((r0 >> 4) + (s_ >> 1)) * 4 + n) << 8) + tl * 16 + (s_ & 1) * 8;
        *(bf16x8*)(vbf + base) = pack;
    }
}

// ---------------------------------------------------------------------------
// Kernel 2: attention. QK^T via K=32 mfma16 (half the QK MFMA instrs and
// dep-chain of r13's K=16 pairs; 16x16 C/D layout is shape-independent so
// S^T still lands in P's K=16 A-layout -> transpose-free PV). grid = 2048 =
// qtile(256) x bg(8), 4 waves/block, wave owns 256 keys = 8 iters of 32.
// K register double-buffer via unroll-by-2 pointer swap (no per-iter movs).
__global__ __launch_bounds__(256) void attn_kernel(
    const __hip_bfloat16* __restrict__ qbf,
    const __hip_bfloat16* __restrict__ kbf,
    const __hip_bfloat16* __restrict__ vbf,
    float* __restrict__ Opart, float* __restrict__ lpart)
{
    __shared__ float ored[2][32][65];   // [slab][row][col], pad-65
    __shared__ float lred[2][32];

    const int qtile = blockIdx.x >> 3;
    const int bg    = blockIdx.x & 7;
    const int w     = threadIdx.x >> 6;
    const int lane  = threadIdx.x & 63;
    const int l16   = lane & 15;
    const int quad  = lane >> 4;
    const int r0    = qtile * 32;
    const int fo    = l16 * 16 + quad * 4;                    // K=16 frag offset
    const int fo32  = l16 * 16 + (quad & 1) * 8;              // K=32 frag offset
    const int qh    = quad >> 1;                              // K=32 tile-pair half

    // Q fragments in K=32 form: qf32[u][p] covers d in [p*32, p*32+32)
    bf16x8 qf32[2][2];
    #pragma unroll
    for (int u = 0; u < 2; ++u)
        #pragma unroll
        for (int p = 0; p < 2; ++p)
            qf32[u][p] = *(const bf16x8*)(qbf +
                ((((r0 >> 4) + u) * 4 + p * 2 + qh) << 8) + fo32);

    f32x4 of[2][4];
    float lp[2] = {0.f, 0.f};
    #pragma unroll
    for (int u = 0; u < 2; ++u)
        #pragma unroll
        for (int n = 0; n < 4; ++n)
            of[u][n] = (f32x4){0.f, 0.f, 0.f, 0.f};

    const int ck0 = bg * 64 + w * 16;          // first key 16-chunk
    bf16x8 kfA[2][2], kfB[2][2];
    #pragma unroll
    for (int h = 0; h < 2; ++h)
        #pragma unroll
        for (int p = 0; p < 2; ++p)
            kfA[h][p] = *(const bf16x8*)(kbf +
                (((ck0 + h) * 4 + p * 2 + qh) << 8) + fo32);

    #pragma unroll 1
    for (int it = 0; it < 8; it += 2) {
        #pragma unroll
        for (int st = 0; st < 2; ++st) {
            const int ck = ck0 + (it + st) * 2;
            bf16x8 (&kf)[2][2] = (st == 0) ? kfA : kfB;
            bf16x8 (&kn)[2][2] = (st == 0) ? kfB : kfA;
            // V frags (K=16 form) for current 32 keys
            s16x4 vf[4][2];
            #pragma unroll
            for (int n = 0; n < 4; ++n)
                #pragma unroll
                for (int h = 0; h < 2; ++h)
                    vf[n][h] = *(const s16x4*)(vbf + (((ck + h) * 4 + n) << 8) + fo);
            // prefetch next iteration's K into the other buffer
            const int cnext = (it + st + 1 < 8) ? ck + 2 : ck;
            #pragma unroll
            for (int h = 0; h < 2; ++h)
                #pragma unroll
                for (int p = 0; p < 2; ++p)
                    kn[h][p] = *(const bf16x8*)(kbf +
                        (((cnext + h) * 4 + p * 2 + qh) << 8) + fo32);

            const f32x4 zero = (f32x4){0.f, 0.f, 0.f, 0.f};
            #pragma unroll
            for (int u = 0; u < 2; ++u) {
                // S^T tiles via K=32: D[key=quad*4+r][qrow=l16]
                f32x4 s0 = mfma16(kf[0][0], qf32[u][0], zero);
                s0       = mfma16(kf[0][1], qf32[u][1], s0);
                f32x4 s1 = mfma16(kf[1][0], qf32[u][0], zero);
                s1       = mfma16(kf[1][1], qf32[u][1], s1);
                union { bf16x4 v; s16x4 s; } pf0, pf1;
                #pragma unroll
                for (int r = 0; r < 4; ++r) {
                    float p0 = __builtin_amdgcn_exp2f(s0[r]);   // raw v_exp_f32
                    float p1 = __builtin_amdgcn_exp2f(s1[r]);
                    lp[u] += p0 + p1;
                    pf0.v[r] = (__bf16)p0;
                    pf1.v[r] = (__bf16)p1;
                }
                #pragma unroll
                for (int n = 0; n < 4; ++n) {
                    of[u][n] = mfma1k(pf0.s, vf[n][0], of[u][n]);
                    of[u][n] = mfma1k(pf1.s, vf[n][1], of[u][n]);
                }
            }
        }
    }

    // per-wave l reduction across quads
    #pragma unroll
    for (int u = 0; u < 2; ++u) {
        float v = lp[u];
        v += __shfl_xor(v, 16, 64);
        v += __shfl_xor(v, 32, 64);
        lp[u] = v;
    }

    // 2-slab tree reduction: waves 2,3 -> LDS
    if (w >= 2) {
        #pragma unroll
        for (int u = 0; u < 2; ++u)
            #pragma unroll
            for (int n = 0; n < 4; ++n)
                #pragma unroll
                for (int r = 0; r < 4; ++r)
                    ored[w - 2][u * 16 + quad * 4 + r][n * 16 + l16] = of[u][n][r];
        if (quad == 0) {
            lred[w - 2][l16]      = lp[0];
            lred[w - 2][16 + l16] = lp[1];
        }
    }
    __syncthreads();
    if (w < 2) {
        #pragma unroll
        for (int u = 0; u < 2; ++u)
            #pragma unroll
            for (int n = 0; n < 4; ++n)
                #pragma unroll
                for (int r = 0; r < 4; ++r) {
                    float v = of[u][n][r] + ored[w][u * 16 + quad * 4 + r][n * 16 + l16];
                    ored[w][u * 16 + quad * 4 + r][n * 16 + l16] = v;
                }
        if (quad == 0) {
            lred[w][l16]      += lp[0];
            lred[w][16 + l16] += lp[1];
        }
    }
    __syncthreads();
    const int task = blockIdx.x;
    float* Ob = Opart + (size_t)task * 2048;
    for (int e = threadIdx.x; e < 2048; e += 256) {
        const int row = e >> 6, col = e & 63;
        Ob[e] = ored[0][row][col] + ored[1][row][col];
    }
    if (threadIdx.x < 32)
        lpart[task * 32 + threadIdx.x] = lred[0][threadIdx.x] + lred[1][threadIdx.x];
}

// ---------------------------------------------------------------------------
// Kernel 3: combine 8 partials/tile, divide by l, l2-normalize -> qnb (bf16).
__global__ __launch_bounds__(256) void combine_kernel(
    const float* __restrict__ Opart, const float* __restrict__ lpart,
    __hip_bfloat16* __restrict__ qnb)
{
    const int r    = blockIdx.x * 4 + (threadIdx.x >> 6);
    const int c    = threadIdx.x & 63;
    const int tile = r >> 5, row = r & 31;
    float acc = 0.f, lsum = 0.f;
    #pragma unroll
    for (int g = 0; g < 8; ++g) {
        int task = tile * 8 + g;
        acc  += Opart[(size_t)task * 2048 + row * 64 + c];
        lsum += lpart[task * 32 + row];
    }
    float q = acc / lsum;
    float ss = q * q;
    ss += __shfl_xor(ss, 1, 64);
    ss += __shfl_xor(ss, 2, 64);
    ss += __shfl_xor(ss, 4, 64);
    ss += __shfl_xor(ss, 8, 64);
    ss += __shfl_xor(ss, 16, 64);
    ss += __shfl_xor(ss, 32, 64);
    qnb[(size_t)r * 64 + c] = __float2bfloat16(q * rsqrtf(fmaxf(ss, 1e-24f)));
}

// ---------------------------------------------------------------------------
// Kernel 4: sim = (1/128) * Vn(64x8192) @ Qn(64x8192)^T, split-K MFMA GEMM.
__global__ __launch_bounds__(64) void sim_kernel(
    const __hip_bfloat16* __restrict__ vnb,
    const __hip_bfloat16* __restrict__ qnb,
    float* __restrict__ out)
{
    const int lane = threadIdx.x;
    const int l16  = lane & 15;
    const int quad = lane >> 4;
    const int kblk = blockIdx.x * 256;

    f32x4 acc[4][4];
    #pragma unroll
    for (int mi = 0; mi < 4; ++mi)
        #pragma unroll
        for (int ni = 0; ni < 4; ++ni)
            acc[mi][ni] = (f32x4){0.f, 0.f, 0.f, 0.f};

    #pragma unroll
    for (int ks = 0; ks < 8; ++ks) {
        const int k0 = kblk + ks * 32 + quad * 8;
        bf16x8 af[4], bfv[4];
        #pragma unroll
        for (int mi = 0; mi < 4; ++mi)
            af[mi] = *(const bf16x8*)(vnb + (size_t)(mi * 16 + l16) * 8192 + k0);
        #pragma unroll
        for (int ni = 0; ni < 4; ++ni)
            bfv[ni] = *(const bf16x8*)(qnb + (size_t)(ni * 16 + l16) * 8192 + k0);
        #pragma unroll
        for (int mi = 0; mi < 4; ++mi)
            #pragma unroll
            for (int ni = 0; ni < 4; ++ni)
                acc[mi][ni] = mfma16(af[mi], bfv[ni], acc[mi][ni]);
    }

    #pragma unroll
    for (int mi = 0; mi < 4; ++mi)
        #pragma unroll
        for (int ni = 0; ni < 4; ++ni)
            #pragma unroll
            for (int r = 0; r < 4; ++r)
                atomicAdd(&out[(mi * 16 + quad * 4 + r) * 64 + ni * 16 + l16],
                          acc[mi][ni][r] * (1.f / 128.f));
}

// ---------------------------------------------------------------------------
extern "C" void kernel_launch(void* const* d_in, const int* in_sizes, int n_in,
                              void* d_out, int out_size, void* d_ws, size_t ws_size,
                              hipStream_t stream)
{
    const float* feat = (const float*)d_in[0];
    const float* Wq   = (const float*)d_in[1];
    const float* bq   = (const float*)d_in[2];
    const float* Wk   = (const float*)d_in[3];
    const float* bk   = (const float*)d_in[4];
    const float* Wv   = (const float*)d_in[5];
    const float* bv   = (const float*)d_in[6];
    float* out = (float*)d_out;

    const size_t MB = 1u << 20;
    char* ws = (char*)d_ws;
    __hip_bfloat16* qbf = (__hip_bfloat16*)(ws);              // 1 MB (frag-tiled, pre-scaled)
    __hip_bfloat16* kbf = (__hip_bfloat16*)(ws + 1 * MB);     // 1 MB (frag-tiled)
    __hip_bfloat16* vbf = (__hip_bfloat16*)(ws + 2 * MB);     // 1 MB (frag-tiled)
    __hip_bfloat16* vnb = (__hip_bfloat16*)(ws + 3 * MB);     // 1 MB (row-major)
    float* Opart = (float*)(ws + 4 * MB);                     // 16 MB (2048 x 8 KB)
    float* lpart = (float*)(ws + 20 * MB);                    // 256 KB
    __hip_bfloat16* qnb = (__hip_bfloat16*)(ws + 21 * MB);    // 1 MB

    (void)hipMemsetAsync(out, 0, 64 * 64 * sizeof(float), stream);
    proj_kernel<<<768, 256, 0, stream>>>(feat, Wq, bq, Wk, bk, Wv, bv, qbf, kbf, vbf, vnb);
    attn_kernel<<<2048, 256, 0, stream>>>(qbf, kbf, vbf, Opart, lpart);
    combine_kernel<<<2048, 256, 0, stream>>>(Opart, lpart, qnb);
    sim_kernel<<<32, 64, 0, stream>>>(vnb, qnb, out);
}

// Round 15
// 120.831 us; speedup vs baseline: 1.0972x; 1.0142x over previous
//
#include <hip/hip_runtime.h>
#include <hip/hip_bf16.h>

#define NROW 8192   // B*A = 64*128
#define INC  128
#define OUTC 64

// Q is pre-scaled by log2(e)/sqrt(64) at projection time, so attention
// computes p = exp2(q'.k) with a single v_exp_f32 per score.
#define QSCALE 0.18033688011112042f

typedef __bf16 bf16x8 __attribute__((ext_vector_type(8)));
typedef __bf16 bf16x4 __attribute__((ext_vector_type(4)));
typedef short  s16x4  __attribute__((ext_vector_type(4)));
typedef float  f32x4  __attribute__((ext_vector_type(4)));

static __device__ __forceinline__ f32x4 mfma16(bf16x8 a, bf16x8 b, f32x4 c) {
    return __builtin_amdgcn_mfma_f32_16x16x32_bf16(a, b, c, 0, 0, 0);
}
// 16x16x16 bf16 (K=16). C/D of S^T IS the A-operand layout of P for PV.
static __device__ __forceinline__ f32x4 mfma1k(s16x4 a, s16x4 b, f32x4 c) {
    return __builtin_amdgcn_mfma_f32_16x16x16bf16_1k(a, b, c, 0, 0, 0);
}

static __device__ __forceinline__ bf16x8 cvt8(float4 lo, float4 hi) {
    bf16x8 r;
    r[0] = (__bf16)lo.x; r[1] = (__bf16)lo.y; r[2] = (__bf16)lo.z; r[3] = (__bf16)lo.w;
    r[4] = (__bf16)hi.x; r[5] = (__bf16)hi.y; r[6] = (__bf16)hi.z; r[7] = (__bf16)hi.w;
    return r;
}

// ---------------------------------------------------------------------------
// Kernel 1: projection via MFMA. grid = 768 = mat(3) x b(64) x aq(4).
// Q/K/V written in FRAGMENT-TILED layout (512-B 16x16 tiles), Q pre-scaled.
__global__ __launch_bounds__(256) void proj_kernel(
    const float* __restrict__ feat,
    const float* __restrict__ Wq, const float* __restrict__ bq,
    const float* __restrict__ Wk, const float* __restrict__ bk,
    const float* __restrict__ Wv, const float* __restrict__ bv,
    __hip_bfloat16* __restrict__ qbf, __hip_bfloat16* __restrict__ kbf,
    __hip_bfloat16* __restrict__ vbf, __hip_bfloat16* __restrict__ vnb)
{
    __shared__ float slab[32 * 132];
    __shared__ float vbuf[32 * 66];
    __shared__ float invb[32];

    const int blk = blockIdx.x;
    const int mat = blk >> 8;
    const int b   = (blk >> 2) & 63;
    const int a0  = (blk & 3) * 32;
    const int r0  = b * 128 + a0;
    const float* fb = feat + (size_t)b * INC * 128;

    for (int i = threadIdx.x; i < 32 * 128; i += 256) {
        int c = i >> 5, a = i & 31;
        slab[a * 132 + c] = fb[c * 128 + a0 + a];
    }
    __syncthreads();

    const int w    = threadIdx.x >> 6;
    const int lane = threadIdx.x & 63;
    const int l16  = lane & 15;
    const int quad = lane >> 4;
    const int n0   = w * 16;

    const float* W    = (mat == 0) ? Wq : (mat == 1) ? Wk : Wv;
    const float* bias = (mat == 0) ? bq : (mat == 1) ? bk : bv;

    f32x4 acc[2] = {{0.f,0.f,0.f,0.f},{0.f,0.f,0.f,0.f}};
    #pragma unroll
    for (int kc = 0; kc < 4; ++kc) {
        const int k0 = kc * 32 + quad * 8;
        const float* wr = W + (n0 + l16) * INC + k0;
        bf16x8 bfr = cvt8(*(const float4*)wr, *(const float4*)(wr + 4));
        #pragma unroll
        for (int u = 0; u < 2; ++u) {
            const float* ar = slab + (u * 16 + l16) * 132 + k0;
            bf16x8 afr = cvt8(*(const float4*)ar, *(const float4*)(ar + 4));
            acc[u] = mfma16(afr, bfr, acc[u]);
        }
    }
    const float bl = bias[n0 + l16];
    const float sc = (mat == 0) ? QSCALE : 1.0f;

    if (mat < 2) {
        __hip_bfloat16* dst = mat ? kbf : qbf;
        #pragma unroll
        for (int u = 0; u < 2; ++u) {
            const int base = ((((r0 >> 4) + u) * 4 + w) << 8) + l16;
            #pragma unroll
            for (int r = 0; r < 4; ++r)
                dst[base + (quad * 4 + r) * 16] = __float2bfloat16((acc[u][r] + bl) * sc);
        }
    } else {
        #pragma unroll
        for (int u = 0; u < 2; ++u)
            #pragma unroll
            for (int r = 0; r < 4; ++r)
                vbuf[(u * 16 + quad * 4 + r) * 66 + n0 + l16] = acc[u][r] + bl;
        __syncthreads();
        const int rl = threadIdx.x >> 3;
        const int jj = threadIdx.x & 7;
        float ss = 0.f;
        #pragma unroll
        for (int i = 0; i < 8; ++i) {
            float x = vbuf[rl * 66 + jj * 8 + i];
            ss += x * x;
        }
        ss += __shfl_xor(ss, 1, 64);
        ss += __shfl_xor(ss, 2, 64);
        ss += __shfl_xor(ss, 4, 64);
        if (jj == 0) invb[rl] = rsqrtf(fmaxf(ss, 1e-24f));
        __syncthreads();
        float inv = invb[rl];
        bf16x8 vp;
        #pragma unroll
        for (int i = 0; i < 8; ++i)
            vp[i] = (__bf16)(vbuf[rl * 66 + jj * 8 + i] * inv);
        *(bf16x8*)(vnb + (size_t)(r0 + rl) * 64 + jj * 8) = vp;
        const int tl = threadIdx.x & 15;
        const int n  = (threadIdx.x >> 4) & 3;
        const int s_ = threadIdx.x >> 6;
        bf16x8 pack;
        #pragma unroll
        for (int j = 0; j < 8; ++j) {
            int key = s_ * 8 + j;
            pack[j] = (__bf16)(vbuf[key * 66 + n * 16 + tl] * invb[key]);
        }
        const int base = ((((r0 >> 4) + (s_ >> 1)) * 4 + n) << 8) + tl * 16 + (s_ & 1) * 8;
        *(bf16x8*)(vbf + base) = pack;
    }
}

// ---------------------------------------------------------------------------
// Kernel 2: attention. grid = 512 = qb(64) x bg(8); block = 128 q-rows x
// 1024 keys. The 4 waves share the SAME key stream (identical K/V addresses
// -> L1 hits for 3 of 4 waves; previously waves split keys -> 537 MB of
// private L2 reads) and own distinct 32-row q-subtiles -> no epilogue
// reduction, zero LDS. All frag loads are ptr+immediate (byte pointers
// advanced +4096/iter) -> address VALU ~16 cyc/iter vs ~400 before.
__global__ __launch_bounds__(256) void attn_kernel(
    const __hip_bfloat16* __restrict__ qbf,
    const __hip_bfloat16* __restrict__ kbf,
    const __hip_bfloat16* __restrict__ vbf,
    float* __restrict__ Opart, float* __restrict__ lpart)
{
    const int qb    = blockIdx.x >> 3;
    const int bg    = blockIdx.x & 7;
    const int w     = threadIdx.x >> 6;
    const int lane  = threadIdx.x & 63;
    const int l16   = lane & 15;
    const int quad  = lane >> 4;
    const int r0    = qb * 128 + w * 32;
    const int fo    = l16 * 16 + quad * 4;            // K=16 frag elem offset
    const int fo32  = l16 * 16 + (quad & 1) * 8;      // K=32 frag elem offset
    const int qh    = quad >> 1;                      // K=32 tile-pair half

    // Q fragments in K=32 form
    bf16x8 qf32[2][2];
    #pragma unroll
    for (int u = 0; u < 2; ++u)
        #pragma unroll
        for (int p = 0; p < 2; ++p)
            qf32[u][p] = *(const bf16x8*)(qbf +
                ((((r0 >> 4) + u) * 4 + p * 2 + qh) << 8) + fo32);

    f32x4 of[2][4];
    float lp[2] = {0.f, 0.f};
    #pragma unroll
    for (int u = 0; u < 2; ++u)
        #pragma unroll
        for (int n = 0; n < 4; ++n)
            of[u][n] = (f32x4){0.f, 0.f, 0.f, 0.f};

    // byte pointers: chunk stride 2048 B, iteration (2 chunks) stride 4096 B
    const int ck0 = bg * 64;                          // 64 chunks = 1024 keys
    const char* kp = (const char*)kbf + ck0 * 2048 + qh * 512 + fo32 * 2;
    const char* vp = (const char*)vbf + ck0 * 2048 + fo * 2;

    bf16x8 kfA[2][2], kfB[2][2];
    #pragma unroll
    for (int h = 0; h < 2; ++h)
        #pragma unroll
        for (int p = 0; p < 2; ++p)
            kfA[h][p] = *(const bf16x8*)(kp + h * 2048 + p * 1024);
    kp += 4096;

    #pragma unroll 1
    for (int body = 0; body < 16; ++body) {
        #pragma unroll
        for (int st = 0; st < 2; ++st) {
            bf16x8 (&kf)[2][2] = (st == 0) ? kfA : kfB;
            bf16x8 (&kn)[2][2] = (st == 0) ? kfB : kfA;
            // V frags (K=16 form), immediate offsets
            s16x4 vf[4][2];
            #pragma unroll
            for (int n = 0; n < 4; ++n)
                #pragma unroll
                for (int h = 0; h < 2; ++h)
                    vf[n][h] = *(const s16x4*)(vp + h * 2048 + n * 512);
            // prefetch next iteration's K (stray read past range is harmless)
            #pragma unroll
            for (int h = 0; h < 2; ++h)
                #pragma unroll
                for (int p = 0; p < 2; ++p)
                    kn[h][p] = *(const bf16x8*)(kp + h * 2048 + p * 1024);
            vp += 4096;
            kp += 4096;

            const f32x4 zero = (f32x4){0.f, 0.f, 0.f, 0.f};
            #pragma unroll
            for (int u = 0; u < 2; ++u) {
                f32x4 s0 = mfma16(kf[0][0], qf32[u][0], zero);
                s0       = mfma16(kf[0][1], qf32[u][1], s0);
                f32x4 s1 = mfma16(kf[1][0], qf32[u][0], zero);
                s1       = mfma16(kf[1][1], qf32[u][1], s1);
                union { bf16x4 v; s16x4 s; } pf0, pf1;
                #pragma unroll
                for (int r = 0; r < 4; ++r) {
                    float p0 = __builtin_amdgcn_exp2f(s0[r]);   // raw v_exp_f32
                    float p1 = __builtin_amdgcn_exp2f(s1[r]);
                    lp[0 + u] += p0 + p1;
                    pf0.v[r] = (__bf16)p0;
                    pf1.v[r] = (__bf16)p1;
                }
                #pragma unroll
                for (int n = 0; n < 4; ++n) {
                    of[u][n] = mfma1k(pf0.s, vf[n][0], of[u][n]);
                    of[u][n] = mfma1k(pf1.s, vf[n][1], of[u][n]);
                }
            }
        }
    }

    // per-wave l reduction across quads
    #pragma unroll
    for (int u = 0; u < 2; ++u) {
        float v = lp[u];
        v += __shfl_xor(v, 16, 64);
        v += __shfl_xor(v, 32, 64);
        lp[u] = v;
    }

    // streaming per-wave partial: tile = qb*4 + w owns rows [r0, r0+32)
    const int task = (qb * 4 + w) * 8 + bg;
    float* Ob = Opart + (size_t)task * 2048;
    #pragma unroll
    for (int u = 0; u < 2; ++u)
        #pragma unroll
        for (int n = 0; n < 4; ++n)
            #pragma unroll
            for (int r = 0; r < 4; ++r)
                Ob[(u * 16 + quad * 4 + r) * 64 + n * 16 + l16] = of[u][n][r];
    if (quad == 0) {
        lpart[task * 32 + l16]      = lp[0];
        lpart[task * 32 + 16 + l16] = lp[1];
    }
}

// ---------------------------------------------------------------------------
// Kernel 3: combine 8 partials/tile, divide by l, l2-normalize -> qnb (bf16).
__global__ __launch_bounds__(256) void combine_kernel(
    const float* __restrict__ Opart, const float* __restrict__ lpart,
    __hip_bfloat16* __restrict__ qnb)
{
    const int r    = blockIdx.x * 4 + (threadIdx.x >> 6);
    const int c    = threadIdx.x & 63;
    const int tile = r >> 5, row = r & 31;
    float acc = 0.f, lsum = 0.f;
    #pragma unroll
    for (int g = 0; g < 8; ++g) {
        int task = tile * 8 + g;
        acc  += Opart[(size_t)task * 2048 + row * 64 + c];
        lsum += lpart[task * 32 + row];
    }
    float q = acc / lsum;
    float ss = q * q;
    ss += __shfl_xor(ss, 1, 64);
    ss += __shfl_xor(ss, 2, 64);
    ss += __shfl_xor(ss, 4, 64);
    ss += __shfl_xor(ss, 8, 64);
    ss += __shfl_xor(ss, 16, 64);
    ss += __shfl_xor(ss, 32, 64);
    qnb[(size_t)r * 64 + c] = __float2bfloat16(q * rsqrtf(fmaxf(ss, 1e-24f)));
}

// ---------------------------------------------------------------------------
// Kernel 4: sim = (1/128) * Vn(64x8192) @ Qn(64x8192)^T, split-K MFMA GEMM.
__global__ __launch_bounds__(64) void sim_kernel(
    const __hip_bfloat16* __restrict__ vnb,
    const __hip_bfloat16* __restrict__ qnb,
    float* __restrict__ out)
{
    const int lane = threadIdx.x;
    const int l16  = lane & 15;
    const int quad = lane >> 4;
    const int kblk = blockIdx.x * 256;

    f32x4 acc[4][4];
    #pragma unroll
    for (int mi = 0; mi < 4; ++mi)
        #pragma unroll
        for (int ni = 0; ni < 4; ++ni)
            acc[mi][ni] = (f32x4){0.f, 0.f, 0.f, 0.f};

    #pragma unroll
    for (int ks = 0; ks < 8; ++ks) {
        const int k0 = kblk + ks * 32 + quad * 8;
        bf16x8 af[4], bfv[4];
        #pragma unroll
        for (int mi = 0; mi < 4; ++mi)
            af[mi] = *(const bf16x8*)(vnb + (size_t)(mi * 16 + l16) * 8192 + k0);
        #pragma unroll
        for (int ni = 0; ni < 4; ++ni)
            bfv[ni] = *(const bf16x8*)(qnb + (size_t)(ni * 16 + l16) * 8192 + k0);
        #pragma unroll
        for (int mi = 0; mi < 4; ++mi)
            #pragma unroll
            for (int ni = 0; ni < 4; ++ni)
                acc[mi][ni] = mfma16(af[mi], bfv[ni], acc[mi][ni]);
    }

    #pragma unroll
    for (int mi = 0; mi < 4; ++mi)
        #pragma unroll
        for (int ni = 0; ni < 4; ++ni)
            #pragma unroll
            for (int r = 0; r < 4; ++r)
                atomicAdd(&out[(mi * 16 + quad * 4 + r) * 64 + ni * 16 + l16],
                          acc[mi][ni][r] * (1.f / 128.f));
}

// ---------------------------------------------------------------------------
extern "C" void kernel_launch(void* const* d_in, const int* in_sizes, int n_in,
                              void* d_out, int out_size, void* d_ws, size_t ws_size,
                              hipStream_t stream)
{
    const float* feat = (const float*)d_in[0];
    const float* Wq   = (const float*)d_in[1];
    const float* bq   = (const float*)d_in[2];
    const float* Wk   = (const float*)d_in[3];
    const float* bk   = (const float*)d_in[4];
    const float* Wv   = (const float*)d_in[5];
    const float* bv   = (const float*)d_in[6];
    float* out = (float*)d_out;

    const size_t MB = 1u << 20;
    char* ws = (char*)d_ws;
    __hip_bfloat16* qbf = (__hip_bfloat16*)(ws);              // 1 MB (frag-tiled, pre-scaled)
    __hip_bfloat16* kbf = (__hip_bfloat16*)(ws + 1 * MB);     // 1 MB (frag-tiled)
    __hip_bfloat16* vbf = (__hip_bfloat16*)(ws + 2 * MB);     // 1 MB (frag-tiled)
    __hip_bfloat16* vnb = (__hip_bfloat16*)(ws + 3 * MB);     // 1 MB (row-major)
    float* Opart = (float*)(ws + 4 * MB);                     // 16 MB (2048 x 8 KB)
    float* lpart = (float*)(ws + 20 * MB);                    // 256 KB
    __hip_bfloat16* qnb = (__hip_bfloat16*)(ws + 21 * MB);    // 1 MB

    (void)hipMemsetAsync(out, 0, 64 * 64 * sizeof(float), stream);
    proj_kernel<<<768, 256, 0, stream>>>(feat, Wq, bq, Wk, bk, Wv, bv, qbf, kbf, vbf, vnb);
    attn_kernel<<<512, 256, 0, stream>>>(qbf, kbf, vbf, Opart, lpart);
    combine_kernel<<<2048, 256, 0, stream>>>(Opart, lpart, qnb);
    sim_kernel<<<32, 64, 0, stream>>>(vnb, qnb, out);
}